// Round 18
// baseline (233.927 us; speedup 1.0000x reference)
//
#include <hip/hip_runtime.h>
#include <hip/hip_bf16.h>

typedef __attribute__((ext_vector_type(8))) short short8v;
typedef __attribute__((ext_vector_type(4))) float f32x4;

// Activation storage: separate hi/lo bf16 planes, stride 128 shorts (256 B).
// feats 0..99 valid, 100..127 zero pad.
#define PST 128
#define PSTL 136   // LDS row stride (shorts): 272B = 16B-aligned, 4-bank row skew
#define MAXBUCK 1024
#define BCAP 8192  // padded tmpv capacity per bucket (mean 4096, sd 64 -> safe)

static __device__ inline unsigned short f2bf(float x) {
    union { float f; unsigned int u; } c; c.f = x;
    unsigned int r = (c.u + 0x7FFFu + ((c.u >> 16) & 1u)) >> 16;
    return (unsigned short)r;
}
static __device__ inline float bf2f(unsigned short h) {
    union { float f; unsigned int u; } c; c.u = ((unsigned int)h) << 16;
    return c.f;
}
static __device__ inline f32x4 MF(short8v a, short8v b, f32x4 c) {
    return __builtin_amdgcn_mfma_f32_16x16x32_bf16(a, b, c, 0, 0, 0);
}
static __device__ inline void acc8(float (&a)[8], short8v v) {
#pragma unroll
    for (int m = 0; m < 8; ++m) a[m] += bf2f((unsigned short)v[m]);
}

// ---------------- bucket CSR build (bucket = dst>>8, 256 nodes) -------------
// Single pass over edges: pre-sort (src<<8|dst&255) into capacity-padded tmpv
// (per-block LDS staging, bucket counts in bcur). No k_bincount pass.
__global__ __launch_bounds__(256) void k_binscatter(const int* __restrict__ src,
                                                    const int* __restrict__ dst,
                                                    int* __restrict__ bcur,
                                                    int* __restrict__ tmpv,
                                                    int n, int nbuck, int chunk) {
    __shared__ int lcnt[MAXBUCK];
    __shared__ int lbase[MAXBUCK];
    int t = threadIdx.x;
    for (int b = t; b < nbuck; b += 256) lcnt[b] = 0;
    __syncthreads();
    int e0 = blockIdx.x * chunk;
    int e1 = e0 + chunk; if (e1 > n) e1 = n;
    for (int e = e0 + t; e < e1; e += 256) atomicAdd(&lcnt[dst[e] >> 8], 1);
    __syncthreads();
    for (int b = t; b < nbuck; b += 256) {
        int c = lcnt[b];
        lbase[b] = c ? atomicAdd(&bcur[b], c) : 0;   // bcur = running COUNT
        lcnt[b] = 0;  // reuse as local cursor
    }
    __syncthreads();
    for (int e = e0 + t; e < e1; e += 256) {
        int d = dst[e];
        int b = d >> 8;
        int r = atomicAdd(&lcnt[b], 1);
        tmpv[(size_t)b * BCAP + lbase[b] + r] = (src[e] << 8) | (d & 255);
    }
}

// prefix bucket counts -> bbase; set rowp[n_nodes]
__global__ __launch_bounds__(1024) void k_binscan(const int* __restrict__ bcur,
                                                  int* __restrict__ bbase,
                                                  int* __restrict__ rowp,
                                                  int nbuck, int n_nodes, int n_edges) {
    __shared__ int tmp[1024];
    int t = threadIdx.x;
    int v = (t < nbuck) ? bcur[t] : 0;
    tmp[t] = v;
    __syncthreads();
    for (int off = 1; off < 1024; off <<= 1) {
        int u = 0;
        if (t >= off) u = tmp[t - off];
        __syncthreads();
        if (t >= off) tmp[t] += u;
        __syncthreads();
    }
    if (t < nbuck) bbase[t] = tmp[t] - v;
    if (t == 0) rowp[n_nodes] = n_edges;
}

// one block per bucket: LDS histogram+scan -> rowp/inv slice + compact ssrc,
// plus degree-grouped node permutation (counting sort by clamped degree).
__global__ __launch_bounds__(256) void k_build(const int* __restrict__ tmpv,
                                               const int* __restrict__ bbase,
                                               const int* __restrict__ bcur,
                                               int* __restrict__ rowp,
                                               float* __restrict__ inv,
                                               int* __restrict__ ssrc,
                                               int* __restrict__ perm,
                                               int n_nodes, int nbuck) {
    __shared__ int hist[256];
    __shared__ int scan[256];
    __shared__ int curs[256];
    __shared__ int dcur[64];
    int b = blockIdx.x;
    int t = threadIdx.x;
    int s = bbase[b];
    int cnt = bcur[b];
    const int* tv = tmpv + (size_t)b * BCAP;
    hist[t] = 0;
    __syncthreads();
    for (int i = t; i < cnt; i += 256) atomicAdd(&hist[tv[i] & 255], 1);
    __syncthreads();
    int v = hist[t];
    scan[t] = v;
    __syncthreads();
    for (int off = 1; off < 256; off <<= 1) {
        int u = 0;
        if (t >= off) u = scan[t - off];
        __syncthreads();
        if (t >= off) scan[t] += u;
        __syncthreads();
    }
    int excl = scan[t] - v;
    curs[t] = excl;
    int node = (b << 8) + t;
    const bool valid = (node < n_nodes);
    if (valid) {
        rowp[node] = s + excl;
        inv[node] = 1.0f / (float)(v > 1 ? v : 1);
    }
    perm[node] = -1;  // default; valid ranks overwrite below
    __syncthreads();
    for (int i = t; i < cnt; i += 256) {
        int p = tv[i];
        int r = atomicAdd(&curs[p & 255], 1);
        ssrc[s + r] = p >> 8;
    }
    // ---- degree-grouped permutation within the bucket ----
    if (t < 64) dcur[t] = 0;
    __syncthreads();
    int dcl = v > 63 ? 63 : v;
    if (valid) atomicAdd(&dcur[dcl], 1);
    __syncthreads();
    if (t == 0) {
        int c = 0;
        for (int q = 0; q < 64; ++q) { int h = dcur[q]; dcur[q] = c; c += h; }
    }
    __syncthreads();
    if (valid) {
        int rank = atomicAdd(&dcur[dcl], 1);
        perm[(b << 8) + rank] = node;
    }
}

// ---------------- x (fp32) -> hi/lo planes ----------------
__global__ __launch_bounds__(256) void k_cvt(const float* __restrict__ X,
                                             unsigned short* __restrict__ Xhi,
                                             unsigned short* __restrict__ Xlo,
                                             int n) {
    int grp = threadIdx.x >> 4, l = threadIdx.x & 15;
    int i = blockIdx.x * 16 + grp;
    if (i >= n) return;
    unsigned short* ph = Xhi + (size_t)i * PST + l * 8;
    unsigned short* pl = Xlo + (size_t)i * PST + l * 8;
    if (l < 13) {
        float4 v0 = *(const float4*)(X + (size_t)i * 100 + l * 8);
        float4 v1 = (l < 12) ? *(const float4*)(X + (size_t)i * 100 + l * 8 + 4)
                             : make_float4(0.f, 0.f, 0.f, 0.f);
        float f[8] = {v0.x, v0.y, v0.z, v0.w, v1.x, v1.y, v1.z, v1.w};
        short8v hv, lv;
#pragma unroll
        for (int m = 0; m < 8; ++m) {
            unsigned short h = f2bf(f[m]);
            hv[m] = (short)h;
            lv[m] = (short)f2bf(f[m] - bf2f(h));
        }
        *(short8v*)ph = hv;
        *(short8v*)pl = lv;
    } else {
        short8v z = (short8v){0,0,0,0,0,0,0,0};
        *(short8v*)ph = z;
        *(short8v*)pl = z;
    }
}

// ---------------- weight pack (all 3 layers in one launch) ----------------
#define PACKN (2 * 4 * 7 * 64)
__global__ __launch_bounds__(256) void k_pack3(const float* __restrict__ W1l, const float* __restrict__ W1r,
                                               const float* __restrict__ W2l, const float* __restrict__ W2r,
                                               const float* __restrict__ W3l, const float* __restrict__ W3r,
                                               unsigned short* __restrict__ B1h, unsigned short* __restrict__ B1l,
                                               unsigned short* __restrict__ B2h, unsigned short* __restrict__ B2l,
                                               unsigned short* __restrict__ B3h, unsigned short* __restrict__ B3l) {
    int gid = blockIdx.x * 256 + threadIdx.x;
    if (gid >= 3 * PACKN) return;
    int layer = gid / PACKN;
    int idx = gid - layer * PACKN;
    const float* Wl = layer == 0 ? W1l : (layer == 1 ? W2l : W3l);
    const float* Wr = layer == 0 ? W1r : (layer == 1 ? W2r : W3r);
    unsigned short* Bh = layer == 0 ? B1h : (layer == 1 ? B2h : B3h);
    unsigned short* Bl = layer == 0 ? B1l : (layer == 1 ? B2l : B3l);
    int lane = idx & 63;
    int t = idx >> 6;
    int nt = t % 7;
    int pc = t / 7;
    int part = pc >> 2, c = pc & 3;
    int col = nt * 16 + (lane & 15);
    int fbase = c * 32 + (lane >> 4) * 8;
    const float* W = part ? Wr : Wl;
    for (int jj = 0; jj < 8; ++jj) {
        int k = fbase + jj;
        float w = (k < 100 && col < 100) ? W[k * 100 + col] : 0.f;
        unsigned short h = f2bf(w);
        Bh[(size_t)idx * 8 + jj] = h;
        Bl[(size_t)idx * 8 + jj] = f2bf(w - bf2f(h));
    }
}

// ---------------- fused layer: wave-private aggr (LDS) + MFMA GEMM ----------
// 32 nodes / 128 threads / 2 INDEPENDENT waves (R15 structure). Nodes are
// processed in degree-grouped perm order so a wave's 16 nodes have similar
// degrees (kills the max-over-group divergence tax on the edge loop).
__global__ __launch_bounds__(128) void k_layer(const unsigned short* __restrict__ Xhi,
                                               const unsigned short* __restrict__ Xlo,
                                               const int* __restrict__ ssrc,
                                               const int* __restrict__ rowp,
                                               const float* __restrict__ inv,
                                               const int* __restrict__ perm,
                                               const unsigned short* __restrict__ Bh,
                                               const unsigned short* __restrict__ Bl,
                                               const float* __restrict__ bias,
                                               unsigned short* __restrict__ Ohi,
                                               unsigned short* __restrict__ Olo,
                                               int relu, int n) {
    __shared__ unsigned short lds_h[32][PSTL];
    __shared__ unsigned short lds_l[32][PSTL];
    const int t = threadIdx.x;
    const int wv = t >> 6;
    const int lane = t & 63;
    const int base = blockIdx.x * 32;

    // ---- phase 1: this wave gathers its 16 perm'd nodes (4 grp x 4 it) ----
    {
        const int grp = lane >> 4, l = lane & 15;
        const bool act = l < 13;
        const size_t loff = (size_t)l * 8;
        const short8v z = (short8v){0,0,0,0,0,0,0,0};
#pragma unroll
        for (int it = 0; it < 4; ++it) {
            const int lr = wv * 16 + it * 4 + grp;  // LDS row owned by this wave
            const int pn = perm[base + lr];
            if (pn >= 0) {
                const int s = rowp[pn];
                const int e = rowp[pn + 1];
                float a[8];
#pragma unroll
                for (int m = 0; m < 8; ++m) a[m] = 0.f;

                int i = s;
                int j0 = 0, j1 = 0, j2 = 0, j3 = 0, j4 = 0, j5 = 0, j6 = 0, j7 = 0;
                if (i + 8 <= e) {
                    j0 = ssrc[i];     j1 = ssrc[i + 1];
                    j2 = ssrc[i + 2]; j3 = ssrc[i + 3];
                    j4 = ssrc[i + 4]; j5 = ssrc[i + 5];
                    j6 = ssrc[i + 6]; j7 = ssrc[i + 7];
                }
                while (i + 8 <= e) {
                    const int ni = i + 8;
                    int k0 = 0, k1 = 0, k2 = 0, k3 = 0, k4 = 0, k5 = 0, k6 = 0, k7 = 0;
                    if (ni + 8 <= e) {
                        k0 = ssrc[ni];     k1 = ssrc[ni + 1];
                        k2 = ssrc[ni + 2]; k3 = ssrc[ni + 3];
                        k4 = ssrc[ni + 4]; k5 = ssrc[ni + 5];
                        k6 = ssrc[ni + 6]; k7 = ssrc[ni + 7];
                    }
                    if (act) {
                        short8v v0 = *(const short8v*)(Xhi + (size_t)j0 * PST + loff);
                        short8v v1 = *(const short8v*)(Xhi + (size_t)j1 * PST + loff);
                        short8v v2 = *(const short8v*)(Xhi + (size_t)j2 * PST + loff);
                        short8v v3 = *(const short8v*)(Xhi + (size_t)j3 * PST + loff);
                        short8v v4 = *(const short8v*)(Xhi + (size_t)j4 * PST + loff);
                        short8v v5 = *(const short8v*)(Xhi + (size_t)j5 * PST + loff);
                        short8v v6 = *(const short8v*)(Xhi + (size_t)j6 * PST + loff);
                        short8v v7 = *(const short8v*)(Xhi + (size_t)j7 * PST + loff);
                        acc8(a, v0); acc8(a, v1); acc8(a, v2); acc8(a, v3);
                        acc8(a, v4); acc8(a, v5); acc8(a, v6); acc8(a, v7);
                    }
                    j0 = k0; j1 = k1; j2 = k2; j3 = k3;
                    j4 = k4; j5 = k5; j6 = k6; j7 = k7;
                    i = ni;
                }
                if (i + 4 <= e) {
                    int s0 = ssrc[i], s1 = ssrc[i + 1], s2 = ssrc[i + 2], s3 = ssrc[i + 3];
                    if (act) {
                        short8v v0 = *(const short8v*)(Xhi + (size_t)s0 * PST + loff);
                        short8v v1 = *(const short8v*)(Xhi + (size_t)s1 * PST + loff);
                        short8v v2 = *(const short8v*)(Xhi + (size_t)s2 * PST + loff);
                        short8v v3 = *(const short8v*)(Xhi + (size_t)s3 * PST + loff);
                        acc8(a, v0); acc8(a, v1); acc8(a, v2); acc8(a, v3);
                    }
                    i += 4;
                }
                for (; i < e; ++i) {
                    int s0 = ssrc[i];
                    if (act) {
                        short8v v0 = *(const short8v*)(Xhi + (size_t)s0 * PST + loff);
                        acc8(a, v0);
                    }
                }

                if (act) {
                    const float f = inv[pn];
                    short8v hv, lv;
#pragma unroll
                    for (int m = 0; m < 8; ++m) {
                        float v = a[m] * f;
                        unsigned short h = f2bf(v);
                        hv[m] = (short)h;
                        lv[m] = (short)f2bf(v - bf2f(h));
                    }
                    *(short8v*)&lds_h[lr][l * 8] = hv;
                    *(short8v*)&lds_l[lr][l * 8] = lv;
                } else {  // lanes 13..15 zero pad cols 104..127
                    *(short8v*)&lds_h[lr][l * 8] = z;
                    *(short8v*)&lds_l[lr][l * 8] = z;
                }
            } else {  // zero whole LDS row (cols 0..127)
                *(short8v*)&lds_h[lr][l * 8] = z;
                *(short8v*)&lds_l[lr][l * 8] = z;
            }
        }
    }
    // same-wave producer->consumer: lgkmcnt tracking orders ds_write->ds_read
    __builtin_amdgcn_wave_barrier();

    // ---- phase 2: MFMA GEMM on this wave's 16 perm'd rows ----
    const int m0 = base + wv * 16;
    const int lrow = lane & 15;
    const int lg = lane >> 4;
    const int ldr = wv * 16 + lrow;

    f32x4 acc[7];
#pragma unroll
    for (int nt = 0; nt < 7; ++nt) acc[nt] = (f32x4){0.f, 0.f, 0.f, 0.f};

    const int pn0 = perm[m0 + lrow];
    const int r0 = pn0 < 0 ? 0 : pn0;   // clamped; garbage rows never written
    const size_t b0 = (size_t)r0 * PST + lg * 8;

    // part 0: aggr @ Wl (A-frags from this wave's LDS rows)
#pragma unroll
    for (int c = 0; c < 4; ++c) {
        short8v ah0 = *(const short8v*)&lds_h[ldr][c * 32 + lg * 8];
        short8v al0 = *(const short8v*)&lds_l[ldr][c * 32 + lg * 8];
        const unsigned short* bph = Bh + ((size_t)(c * 7) * 64 + lane) * 8;
        const unsigned short* bpl = Bl + ((size_t)(c * 7) * 64 + lane) * 8;
#pragma unroll
        for (int nt = 0; nt < 7; ++nt) {
            short8v bh = *(const short8v*)(bph + nt * 512);
            short8v bl = *(const short8v*)(bpl + nt * 512);
            acc[nt] = MF(ah0, bh, acc[nt]);
            acc[nt] = MF(ah0, bl, acc[nt]);
            acc[nt] = MF(al0, bh, acc[nt]);
        }
    }
    // part 1: x @ Wr (A-frags from global planes, perm'd rows)
#pragma unroll
    for (int c = 0; c < 4; ++c) {
        short8v ah0 = *(const short8v*)(Xhi + b0 + c * 32);
        short8v al0 = *(const short8v*)(Xlo + b0 + c * 32);
        const unsigned short* bph = Bh + ((size_t)((4 + c) * 7) * 64 + lane) * 8;
        const unsigned short* bpl = Bl + ((size_t)((4 + c) * 7) * 64 + lane) * 8;
#pragma unroll
        for (int nt = 0; nt < 7; ++nt) {
            short8v bh = *(const short8v*)(bph + nt * 512);
            short8v bl = *(const short8v*)(bpl + nt * 512);
            acc[nt] = MF(ah0, bh, acc[nt]);
            acc[nt] = MF(ah0, bl, acc[nt]);
            acc[nt] = MF(al0, bh, acc[nt]);
        }
    }

    // epilogue: C/D layout col=lane&15, row=(lane>>4)*4+reg  [HW-verified]
    int pr[4];
#pragma unroll
    for (int r = 0; r < 4; ++r) pr[r] = perm[m0 + lg * 4 + r];
#pragma unroll
    for (int nt = 0; nt < 7; ++nt) {
        int col = nt * 16 + lrow;
        bool cok = col < 100;
        float bb = cok ? bias[col] : 0.f;
#pragma unroll
        for (int r = 0; r < 4; ++r) {
            if (cok && pr[r] >= 0) {
                float v = acc[nt][r] + bb;
                if (relu) v = fmaxf(v, 0.f);
                unsigned short h = f2bf(v);
                size_t o = (size_t)pr[r] * PST + col;
                Ohi[o] = h;
                Olo[o] = f2bf(v - bf2f(h));
            }
        }
    }
    // zero pad cols 100..127 (both planes); 2 lanes per row, 16 rows/wave
    if (lane < 32) {
        int prow = perm[m0 + (lane >> 1)];
        if (prow >= 0) {
            unsigned short* op = ((lane & 1) == 0 ? Ohi : Olo) + (size_t)prow * PST;
            short4 z4 = {0, 0, 0, 0};
            short8v z = (short8v){0,0,0,0,0,0,0,0};
            *(short4*)(op + 100) = z4;
            *(short8v*)(op + 104) = z;
            *(short8v*)(op + 112) = z;
            *(short8v*)(op + 120) = z;
        }
    }
}

// ---------------- pool + head: 1 block/graph ----------------
__global__ __launch_bounds__(256) void k_pool(const unsigned short* __restrict__ Hhi,
                                              const unsigned short* __restrict__ Hlo,
                                              const int* __restrict__ batch,
                                              const float* __restrict__ Wlin,
                                              const float* __restrict__ blin,
                                              float* __restrict__ out, int n) {
    int g = blockIdx.x;
    int t = threadIdx.x;
    int grp = t >> 4, l = t & 15;
    int lo = 0, hi = n;
    while (lo < hi) { int m = (lo + hi) >> 1; if (batch[m] < g) lo = m + 1; else hi = m; }
    int lo2 = lo, hi2 = n;
    while (lo2 < hi2) { int m = (lo2 + hi2) >> 1; if (batch[m] < g + 1) lo2 = m + 1; else hi2 = m; }

    const bool act = l < 13;
    float a[8];
#pragma unroll
    for (int m = 0; m < 8; ++m) a[m] = 0.f;
    const size_t loff = (size_t)l * 8;
    for (int node = lo + grp; node < lo2; node += 16) {
        if (act) {
            short8v vh = *(const short8v*)(Hhi + (size_t)node * PST + loff);
            short8v vl = *(const short8v*)(Hlo + (size_t)node * PST + loff);
#pragma unroll
            for (int m = 0; m < 8; ++m)
                a[m] += bf2f((unsigned short)vh[m]) + bf2f((unsigned short)vl[m]);
        }
    }

    __shared__ float part[16][13][8];
    if (act) {
#pragma unroll
        for (int m = 0; m < 8; ++m) part[grp][l][m] = a[m];
    }
    __syncthreads();

    __shared__ float gm[104];
    if (t < 104) {
        int fg = t >> 3, m = t & 7;
        float s = 0.f;
#pragma unroll
        for (int q = 0; q < 16; ++q) s += part[q][fg][m];
        float f = (lo2 > lo) ? 1.0f / (float)(lo2 - lo) : 0.0f;
        gm[t] = s * f;
    }
    __syncthreads();
    if (t < 2) {
        float o = blin[t];
        for (int k = 0; k < 100; ++k) o += gm[k] * Wlin[k * 2 + t];
        out[g * 2 + t] = o;
    }
}

// ---------------- launch ----------------

extern "C" void kernel_launch(void* const* d_in, const int* in_sizes, int n_in,
                              void* d_out, int out_size, void* d_ws, size_t ws_size,
                              hipStream_t stream) {
    const float* x    = (const float*)d_in[0];
    const int*   ei   = (const int*)d_in[1];
    const int*   batch= (const int*)d_in[2];
    const float* W1l  = (const float*)d_in[3];
    const float* b1   = (const float*)d_in[4];
    const float* W1r  = (const float*)d_in[5];
    const float* W2l  = (const float*)d_in[6];
    const float* b2   = (const float*)d_in[7];
    const float* W2r  = (const float*)d_in[8];
    const float* W3l  = (const float*)d_in[9];
    const float* b3   = (const float*)d_in[10];
    const float* W3r  = (const float*)d_in[11];
    const float* Wlin = (const float*)d_in[12];
    const float* blin = (const float*)d_in[13];
    float* out = (float*)d_out;

    const int n_nodes  = in_sizes[0] / 100;
    const int n_edges  = in_sizes[1] / 2;
    const int n_graphs = out_size / 2;
    const int* src = ei;
    const int* dst = ei + n_edges;

    char* ws = (char*)d_ws;
    size_t o = 0;
    auto alloc = [&](size_t bytes) { size_t r = o; o = (o + bytes + 255) & ~(size_t)255; return r; };
    const int nbuck = (n_nodes + 255) >> 8;
    int*   rowp = (int*)(ws + alloc((size_t)(n_nodes + 1) * 4));
    float* inv  = (float*)(ws + alloc((size_t)n_nodes * 4));
    int*   ssrc = (int*)(ws + alloc((size_t)n_edges * 4));
    int*   perm = (int*)(ws + alloc((size_t)nbuck * 256 * 4));
    int*   bbase= (int*)(ws + alloc(MAXBUCK * 4));
    int*   bcur = (int*)(ws + alloc(MAXBUCK * 4));
    int*   tmpv = (int*)(ws + alloc((size_t)nbuck * BCAP * 4));
    const size_t pbytes = (size_t)n_nodes * PST * 2;  // one bf16 plane
    unsigned short* XAhi = (unsigned short*)(ws + alloc(pbytes));
    unsigned short* XAlo = (unsigned short*)(ws + alloc(pbytes));
    unsigned short* XBhi = (unsigned short*)(ws + alloc(pbytes));
    unsigned short* XBlo = (unsigned short*)(ws + alloc(pbytes));
    const size_t bfb = (size_t)PACKN * 8 * 2;
    unsigned short* B1h = (unsigned short*)(ws + alloc(bfb));
    unsigned short* B1l = (unsigned short*)(ws + alloc(bfb));
    unsigned short* B2h = (unsigned short*)(ws + alloc(bfb));
    unsigned short* B2l = (unsigned short*)(ws + alloc(bfb));
    unsigned short* B3h = (unsigned short*)(ws + alloc(bfb));
    unsigned short* B3l = (unsigned short*)(ws + alloc(bfb));

    hipMemsetAsync(bcur, 0, MAXBUCK * 4, stream);

    const int chunk = (n_edges + 255) / 256;

    // bucket CSR build: single edge pass (padded pre-sort) + tiny scan + build
    k_binscatter<<<256, 256, 0, stream>>>(src, dst, bcur, tmpv, n_edges, nbuck, chunk);
    k_binscan<<<1, 1024, 0, stream>>>(bcur, bbase, rowp, nbuck, n_nodes, n_edges);
    k_build<<<nbuck, 256, 0, stream>>>(tmpv, bbase, bcur, rowp, inv, ssrc, perm,
                                       n_nodes, nbuck);

    k_pack3<<<(3 * PACKN + 255) / 256, 256, 0, stream>>>(
        W1l, W1r, W2l, W2r, W3l, W3r, B1h, B1l, B2h, B2l, B3h, B3l);

    const int nb16 = (n_nodes + 15) / 16;
    const int lgrid = (n_nodes + 31) / 32;

    k_cvt<<<nb16, 256, 0, stream>>>(x, XAhi, XAlo, n_nodes);

    // fused layers: degree-grouped wave-private aggr(LDS) + gemm
    k_layer<<<lgrid, 128, 0, stream>>>(XAhi, XAlo, ssrc, rowp, inv, perm, B1h, B1l, b1,
                                       XBhi, XBlo, 1, n_nodes);
    k_layer<<<lgrid, 128, 0, stream>>>(XBhi, XBlo, ssrc, rowp, inv, perm, B2h, B2l, b2,
                                       XAhi, XAlo, 1, n_nodes);
    k_layer<<<lgrid, 128, 0, stream>>>(XAhi, XAlo, ssrc, rowp, inv, perm, B3h, B3l, b3,
                                       XBhi, XBlo, 0, n_nodes);

    k_pool<<<n_graphs, 256, 0, stream>>>(XBhi, XBlo, batch, Wlin, blin, out, n_nodes);
}

// Round 19
// 220.787 us; speedup vs baseline: 1.0595x; 1.0595x over previous
//
#include <hip/hip_runtime.h>
#include <hip/hip_bf16.h>

typedef __attribute__((ext_vector_type(8))) short short8v;
typedef __attribute__((ext_vector_type(4))) float f32x4;

// Activation storage: separate hi/lo bf16 planes, stride 128 shorts (256 B).
// feats 0..99 valid, 100..127 zero pad.
#define PST 128
#define PSTL 136   // LDS row stride (shorts): 272B = 16B-aligned, 4-bank row skew
#define MAXBUCK 1024
#define BCAP 8192  // padded tmpv capacity per bucket (mean 4096, sd 64 -> safe)

static __device__ inline unsigned short f2bf(float x) {
    union { float f; unsigned int u; } c; c.f = x;
    unsigned int r = (c.u + 0x7FFFu + ((c.u >> 16) & 1u)) >> 16;
    return (unsigned short)r;
}
static __device__ inline float bf2f(unsigned short h) {
    union { float f; unsigned int u; } c; c.u = ((unsigned int)h) << 16;
    return c.f;
}
static __device__ inline f32x4 MF(short8v a, short8v b, f32x4 c) {
    return __builtin_amdgcn_mfma_f32_16x16x32_bf16(a, b, c, 0, 0, 0);
}
static __device__ inline void acc8(float (&a)[8], short8v v) {
#pragma unroll
    for (int m = 0; m < 8; ++m) a[m] += bf2f((unsigned short)v[m]);
}

// ---------------- bucket CSR build (bucket = dst>>8, 256 nodes) -------------
// Single pass over edges: pre-sort (src<<8|dst&255) into capacity-padded tmpv
// (per-block LDS staging, bucket counts in bcur). No k_bincount pass.
__global__ __launch_bounds__(256) void k_binscatter(const int* __restrict__ src,
                                                    const int* __restrict__ dst,
                                                    int* __restrict__ bcur,
                                                    int* __restrict__ tmpv,
                                                    int n, int nbuck, int chunk) {
    __shared__ int lcnt[MAXBUCK];
    __shared__ int lbase[MAXBUCK];
    int t = threadIdx.x;
    for (int b = t; b < nbuck; b += 256) lcnt[b] = 0;
    __syncthreads();
    int e0 = blockIdx.x * chunk;
    int e1 = e0 + chunk; if (e1 > n) e1 = n;
    for (int e = e0 + t; e < e1; e += 256) atomicAdd(&lcnt[dst[e] >> 8], 1);
    __syncthreads();
    for (int b = t; b < nbuck; b += 256) {
        int c = lcnt[b];
        lbase[b] = c ? atomicAdd(&bcur[b], c) : 0;   // bcur = running COUNT
        lcnt[b] = 0;  // reuse as local cursor
    }
    __syncthreads();
    for (int e = e0 + t; e < e1; e += 256) {
        int d = dst[e];
        int b = d >> 8;
        int r = atomicAdd(&lcnt[b], 1);
        tmpv[(size_t)b * BCAP + lbase[b] + r] = (src[e] << 8) | (d & 255);
    }
}

// prefix bucket counts -> bbase; set rowp[n_nodes]
__global__ __launch_bounds__(1024) void k_binscan(const int* __restrict__ bcur,
                                                  int* __restrict__ bbase,
                                                  int* __restrict__ rowp,
                                                  int nbuck, int n_nodes, int n_edges) {
    __shared__ int tmp[1024];
    int t = threadIdx.x;
    int v = (t < nbuck) ? bcur[t] : 0;
    tmp[t] = v;
    __syncthreads();
    for (int off = 1; off < 1024; off <<= 1) {
        int u = 0;
        if (t >= off) u = tmp[t - off];
        __syncthreads();
        if (t >= off) tmp[t] += u;
        __syncthreads();
    }
    if (t < nbuck) bbase[t] = tmp[t] - v;
    if (t == 0) rowp[n_nodes] = n_edges;
}

// one block per bucket: LDS histogram+scan -> rowp/inv slice + compact ssrc
__global__ __launch_bounds__(256) void k_build(const int* __restrict__ tmpv,
                                               const int* __restrict__ bbase,
                                               const int* __restrict__ bcur,
                                               int* __restrict__ rowp,
                                               float* __restrict__ inv,
                                               int* __restrict__ ssrc,
                                               int n_nodes, int nbuck) {
    __shared__ int hist[256];
    __shared__ int scan[256];
    __shared__ int curs[256];
    int b = blockIdx.x;
    int t = threadIdx.x;
    int s = bbase[b];
    int cnt = bcur[b];
    const int* tv = tmpv + (size_t)b * BCAP;
    hist[t] = 0;
    __syncthreads();
    for (int i = t; i < cnt; i += 256) atomicAdd(&hist[tv[i] & 255], 1);
    __syncthreads();
    int v = hist[t];
    scan[t] = v;
    __syncthreads();
    for (int off = 1; off < 256; off <<= 1) {
        int u = 0;
        if (t >= off) u = scan[t - off];
        __syncthreads();
        if (t >= off) scan[t] += u;
        __syncthreads();
    }
    int excl = scan[t] - v;
    curs[t] = excl;
    int node = (b << 8) + t;
    if (node < n_nodes) {
        rowp[node] = s + excl;
        inv[node] = 1.0f / (float)(v > 1 ? v : 1);
    }
    __syncthreads();
    for (int i = t; i < cnt; i += 256) {
        int p = tv[i];
        int r = atomicAdd(&curs[p & 255], 1);
        ssrc[s + r] = p >> 8;
    }
}

// ---------------- x (fp32) -> hi/lo planes ----------------
__global__ __launch_bounds__(256) void k_cvt(const float* __restrict__ X,
                                             unsigned short* __restrict__ Xhi,
                                             unsigned short* __restrict__ Xlo,
                                             int n) {
    int grp = threadIdx.x >> 4, l = threadIdx.x & 15;
    int i = blockIdx.x * 16 + grp;
    if (i >= n) return;
    unsigned short* ph = Xhi + (size_t)i * PST + l * 8;
    unsigned short* pl = Xlo + (size_t)i * PST + l * 8;
    if (l < 13) {
        float4 v0 = *(const float4*)(X + (size_t)i * 100 + l * 8);
        float4 v1 = (l < 12) ? *(const float4*)(X + (size_t)i * 100 + l * 8 + 4)
                             : make_float4(0.f, 0.f, 0.f, 0.f);
        float f[8] = {v0.x, v0.y, v0.z, v0.w, v1.x, v1.y, v1.z, v1.w};
        short8v hv, lv;
#pragma unroll
        for (int m = 0; m < 8; ++m) {
            unsigned short h = f2bf(f[m]);
            hv[m] = (short)h;
            lv[m] = (short)f2bf(f[m] - bf2f(h));
        }
        *(short8v*)ph = hv;
        *(short8v*)pl = lv;
    } else {
        short8v z = (short8v){0,0,0,0,0,0,0,0};
        *(short8v*)ph = z;
        *(short8v*)pl = z;
    }
}

// ---------------- weight pack (all 3 layers in one launch) ----------------
#define PACKN (2 * 4 * 7 * 64)
__global__ __launch_bounds__(256) void k_pack3(const float* __restrict__ W1l, const float* __restrict__ W1r,
                                               const float* __restrict__ W2l, const float* __restrict__ W2r,
                                               const float* __restrict__ W3l, const float* __restrict__ W3r,
                                               unsigned short* __restrict__ B1h, unsigned short* __restrict__ B1l,
                                               unsigned short* __restrict__ B2h, unsigned short* __restrict__ B2l,
                                               unsigned short* __restrict__ B3h, unsigned short* __restrict__ B3l) {
    int gid = blockIdx.x * 256 + threadIdx.x;
    if (gid >= 3 * PACKN) return;
    int layer = gid / PACKN;
    int idx = gid - layer * PACKN;
    const float* Wl = layer == 0 ? W1l : (layer == 1 ? W2l : W3l);
    const float* Wr = layer == 0 ? W1r : (layer == 1 ? W2r : W3r);
    unsigned short* Bh = layer == 0 ? B1h : (layer == 1 ? B2h : B3h);
    unsigned short* Bl = layer == 0 ? B1l : (layer == 1 ? B2l : B3l);
    int lane = idx & 63;
    int t = idx >> 6;
    int nt = t % 7;
    int pc = t / 7;
    int part = pc >> 2, c = pc & 3;
    int col = nt * 16 + (lane & 15);
    int fbase = c * 32 + (lane >> 4) * 8;
    const float* W = part ? Wr : Wl;
    for (int jj = 0; jj < 8; ++jj) {
        int k = fbase + jj;
        float w = (k < 100 && col < 100) ? W[k * 100 + col] : 0.f;
        unsigned short h = f2bf(w);
        Bh[(size_t)idx * 8 + jj] = h;
        Bl[(size_t)idx * 8 + jj] = f2bf(w - bf2f(h));
    }
}

// ---------------- fused layer: wave-private aggr (LDS) + MFMA GEMM ----------
// 32 nodes / 128 threads / 2 INDEPENDENT waves (R15 structure — best measured).
// Gather loop: 8-edge batches with NEXT batch's ssrc indices prefetched while
// current batch's row-loads + accumulation run.
__global__ __launch_bounds__(128) void k_layer(const unsigned short* __restrict__ Xhi,
                                               const unsigned short* __restrict__ Xlo,
                                               const int* __restrict__ ssrc,
                                               const int* __restrict__ rowp,
                                               const float* __restrict__ inv,
                                               const unsigned short* __restrict__ Bh,
                                               const unsigned short* __restrict__ Bl,
                                               const float* __restrict__ bias,
                                               unsigned short* __restrict__ Ohi,
                                               unsigned short* __restrict__ Olo,
                                               int relu, int n) {
    __shared__ unsigned short lds_h[32][PSTL];
    __shared__ unsigned short lds_l[32][PSTL];
    const int t = threadIdx.x;
    const int wv = t >> 6;
    const int lane = t & 63;
    const int base = blockIdx.x * 32;

    // ---- phase 1: this wave gathers its 16 rows (4 groups x 4 iters) ----
    {
        const int grp = lane >> 4, l = lane & 15;
        const bool act = l < 13;
        const size_t loff = (size_t)l * 8;
        const short8v z = (short8v){0,0,0,0,0,0,0,0};
#pragma unroll
        for (int it = 0; it < 4; ++it) {
            const int lr = wv * 16 + it * 4 + grp;  // LDS row owned by this wave
            const int node = base + lr;
            if (node < n) {
                const int s = rowp[node];
                const int e = rowp[node + 1];
                float a[8];
#pragma unroll
                for (int m = 0; m < 8; ++m) a[m] = 0.f;

                int i = s;
                int j0 = 0, j1 = 0, j2 = 0, j3 = 0, j4 = 0, j5 = 0, j6 = 0, j7 = 0;
                if (i + 8 <= e) {
                    j0 = ssrc[i];     j1 = ssrc[i + 1];
                    j2 = ssrc[i + 2]; j3 = ssrc[i + 3];
                    j4 = ssrc[i + 4]; j5 = ssrc[i + 5];
                    j6 = ssrc[i + 6]; j7 = ssrc[i + 7];
                }
                while (i + 8 <= e) {
                    const int ni = i + 8;
                    int k0 = 0, k1 = 0, k2 = 0, k3 = 0, k4 = 0, k5 = 0, k6 = 0, k7 = 0;
                    if (ni + 8 <= e) {
                        k0 = ssrc[ni];     k1 = ssrc[ni + 1];
                        k2 = ssrc[ni + 2]; k3 = ssrc[ni + 3];
                        k4 = ssrc[ni + 4]; k5 = ssrc[ni + 5];
                        k6 = ssrc[ni + 6]; k7 = ssrc[ni + 7];
                    }
                    if (act) {
                        short8v v0 = *(const short8v*)(Xhi + (size_t)j0 * PST + loff);
                        short8v v1 = *(const short8v*)(Xhi + (size_t)j1 * PST + loff);
                        short8v v2 = *(const short8v*)(Xhi + (size_t)j2 * PST + loff);
                        short8v v3 = *(const short8v*)(Xhi + (size_t)j3 * PST + loff);
                        short8v v4 = *(const short8v*)(Xhi + (size_t)j4 * PST + loff);
                        short8v v5 = *(const short8v*)(Xhi + (size_t)j5 * PST + loff);
                        short8v v6 = *(const short8v*)(Xhi + (size_t)j6 * PST + loff);
                        short8v v7 = *(const short8v*)(Xhi + (size_t)j7 * PST + loff);
                        acc8(a, v0); acc8(a, v1); acc8(a, v2); acc8(a, v3);
                        acc8(a, v4); acc8(a, v5); acc8(a, v6); acc8(a, v7);
                    }
                    j0 = k0; j1 = k1; j2 = k2; j3 = k3;
                    j4 = k4; j5 = k5; j6 = k6; j7 = k7;
                    i = ni;
                }
                if (i + 4 <= e) {
                    int s0 = ssrc[i], s1 = ssrc[i + 1], s2 = ssrc[i + 2], s3 = ssrc[i + 3];
                    if (act) {
                        short8v v0 = *(const short8v*)(Xhi + (size_t)s0 * PST + loff);
                        short8v v1 = *(const short8v*)(Xhi + (size_t)s1 * PST + loff);
                        short8v v2 = *(const short8v*)(Xhi + (size_t)s2 * PST + loff);
                        short8v v3 = *(const short8v*)(Xhi + (size_t)s3 * PST + loff);
                        acc8(a, v0); acc8(a, v1); acc8(a, v2); acc8(a, v3);
                    }
                    i += 4;
                }
                for (; i < e; ++i) {
                    int s0 = ssrc[i];
                    if (act) {
                        short8v v0 = *(const short8v*)(Xhi + (size_t)s0 * PST + loff);
                        acc8(a, v0);
                    }
                }

                if (act) {
                    const float f = inv[node];
                    short8v hv, lv;
#pragma unroll
                    for (int m = 0; m < 8; ++m) {
                        float v = a[m] * f;
                        unsigned short h = f2bf(v);
                        hv[m] = (short)h;
                        lv[m] = (short)f2bf(v - bf2f(h));
                    }
                    *(short8v*)&lds_h[lr][l * 8] = hv;
                    *(short8v*)&lds_l[lr][l * 8] = lv;
                } else {  // lanes 13..15 zero pad cols 104..127
                    *(short8v*)&lds_h[lr][l * 8] = z;
                    *(short8v*)&lds_l[lr][l * 8] = z;
                }
            } else {  // zero whole LDS row (cols 0..127)
                *(short8v*)&lds_h[lr][l * 8] = z;
                *(short8v*)&lds_l[lr][l * 8] = z;
            }
        }
    }
    // same-wave producer->consumer: lgkmcnt tracking orders ds_write->ds_read
    __builtin_amdgcn_wave_barrier();

    // ---- phase 2: MFMA GEMM on this wave's 16 rows ----
    const int m0 = base + wv * 16;
    const int lrow = lane & 15;
    const int lg = lane >> 4;
    const int ldr = wv * 16 + lrow;

    f32x4 acc[7];
#pragma unroll
    for (int nt = 0; nt < 7; ++nt) acc[nt] = (f32x4){0.f, 0.f, 0.f, 0.f};

    int r0 = m0 + lrow; if (r0 >= n) r0 = n - 1;
    const size_t b0 = (size_t)r0 * PST + lg * 8;

    // part 0: aggr @ Wl (A-frags from this wave's LDS rows)
#pragma unroll
    for (int c = 0; c < 4; ++c) {
        short8v ah0 = *(const short8v*)&lds_h[ldr][c * 32 + lg * 8];
        short8v al0 = *(const short8v*)&lds_l[ldr][c * 32 + lg * 8];
        const unsigned short* bph = Bh + ((size_t)(c * 7) * 64 + lane) * 8;
        const unsigned short* bpl = Bl + ((size_t)(c * 7) * 64 + lane) * 8;
#pragma unroll
        for (int nt = 0; nt < 7; ++nt) {
            short8v bh = *(const short8v*)(bph + nt * 512);
            short8v bl = *(const short8v*)(bpl + nt * 512);
            acc[nt] = MF(ah0, bh, acc[nt]);
            acc[nt] = MF(ah0, bl, acc[nt]);
            acc[nt] = MF(al0, bh, acc[nt]);
        }
    }
    // part 1: x @ Wr (A-frags from global planes)
#pragma unroll
    for (int c = 0; c < 4; ++c) {
        short8v ah0 = *(const short8v*)(Xhi + b0 + c * 32);
        short8v al0 = *(const short8v*)(Xlo + b0 + c * 32);
        const unsigned short* bph = Bh + ((size_t)((4 + c) * 7) * 64 + lane) * 8;
        const unsigned short* bpl = Bl + ((size_t)((4 + c) * 7) * 64 + lane) * 8;
#pragma unroll
        for (int nt = 0; nt < 7; ++nt) {
            short8v bh = *(const short8v*)(bph + nt * 512);
            short8v bl = *(const short8v*)(bpl + nt * 512);
            acc[nt] = MF(ah0, bh, acc[nt]);
            acc[nt] = MF(ah0, bl, acc[nt]);
            acc[nt] = MF(al0, bh, acc[nt]);
        }
    }

    // epilogue: C/D layout col=lane&15, row=(lane>>4)*4+reg  [HW-verified]
#pragma unroll
    for (int nt = 0; nt < 7; ++nt) {
        int col = nt * 16 + lrow;
        bool cok = col < 100;
        float bb = cok ? bias[col] : 0.f;
#pragma unroll
        for (int r = 0; r < 4; ++r) {
            int row = m0 + lg * 4 + r;
            if (cok && row < n) {
                float v = acc[nt][r] + bb;
                if (relu) v = fmaxf(v, 0.f);
                unsigned short h = f2bf(v);
                size_t o = (size_t)row * PST + col;
                Ohi[o] = h;
                Olo[o] = f2bf(v - bf2f(h));
            }
        }
    }
    // zero pad cols 100..127 (both planes); 2 lanes per row, 16 rows/wave
    if (lane < 32) {
        int row = m0 + (lane >> 1);
        if (row < n) {
            unsigned short* op = ((lane & 1) == 0 ? Ohi : Olo) + (size_t)row * PST;
            short4 z4 = {0, 0, 0, 0};
            short8v z = (short8v){0,0,0,0,0,0,0,0};
            *(short4*)(op + 100) = z4;
            *(short8v*)(op + 104) = z;
            *(short8v*)(op + 112) = z;
            *(short8v*)(op + 120) = z;
        }
    }
}

// ---------------- pool + head: 1 block/graph ----------------
__global__ __launch_bounds__(256) void k_pool(const unsigned short* __restrict__ Hhi,
                                              const unsigned short* __restrict__ Hlo,
                                              const int* __restrict__ batch,
                                              const float* __restrict__ Wlin,
                                              const float* __restrict__ blin,
                                              float* __restrict__ out, int n) {
    int g = blockIdx.x;
    int t = threadIdx.x;
    int grp = t >> 4, l = t & 15;
    int lo = 0, hi = n;
    while (lo < hi) { int m = (lo + hi) >> 1; if (batch[m] < g) lo = m + 1; else hi = m; }
    int lo2 = lo, hi2 = n;
    while (lo2 < hi2) { int m = (lo2 + hi2) >> 1; if (batch[m] < g + 1) lo2 = m + 1; else hi2 = m; }

    const bool act = l < 13;
    float a[8];
#pragma unroll
    for (int m = 0; m < 8; ++m) a[m] = 0.f;
    const size_t loff = (size_t)l * 8;
    for (int node = lo + grp; node < lo2; node += 16) {
        if (act) {
            short8v vh = *(const short8v*)(Hhi + (size_t)node * PST + loff);
            short8v vl = *(const short8v*)(Hlo + (size_t)node * PST + loff);
#pragma unroll
            for (int m = 0; m < 8; ++m)
                a[m] += bf2f((unsigned short)vh[m]) + bf2f((unsigned short)vl[m]);
        }
    }

    __shared__ float part[16][13][8];
    if (act) {
#pragma unroll
        for (int m = 0; m < 8; ++m) part[grp][l][m] = a[m];
    }
    __syncthreads();

    __shared__ float gm[104];
    if (t < 104) {
        int fg = t >> 3, m = t & 7;
        float s = 0.f;
#pragma unroll
        for (int q = 0; q < 16; ++q) s += part[q][fg][m];
        float f = (lo2 > lo) ? 1.0f / (float)(lo2 - lo) : 0.0f;
        gm[t] = s * f;
    }
    __syncthreads();
    if (t < 2) {
        float o = blin[t];
        for (int k = 0; k < 100; ++k) o += gm[k] * Wlin[k * 2 + t];
        out[g * 2 + t] = o;
    }
}

// ---------------- launch ----------------

extern "C" void kernel_launch(void* const* d_in, const int* in_sizes, int n_in,
                              void* d_out, int out_size, void* d_ws, size_t ws_size,
                              hipStream_t stream) {
    const float* x    = (const float*)d_in[0];
    const int*   ei   = (const int*)d_in[1];
    const int*   batch= (const int*)d_in[2];
    const float* W1l  = (const float*)d_in[3];
    const float* b1   = (const float*)d_in[4];
    const float* W1r  = (const float*)d_in[5];
    const float* W2l  = (const float*)d_in[6];
    const float* b2   = (const float*)d_in[7];
    const float* W2r  = (const float*)d_in[8];
    const float* W3l  = (const float*)d_in[9];
    const float* b3   = (const float*)d_in[10];
    const float* W3r  = (const float*)d_in[11];
    const float* Wlin = (const float*)d_in[12];
    const float* blin = (const float*)d_in[13];
    float* out = (float*)d_out;

    const int n_nodes  = in_sizes[0] / 100;
    const int n_edges  = in_sizes[1] / 2;
    const int n_graphs = out_size / 2;
    const int* src = ei;
    const int* dst = ei + n_edges;

    char* ws = (char*)d_ws;
    size_t o = 0;
    auto alloc = [&](size_t bytes) { size_t r = o; o = (o + bytes + 255) & ~(size_t)255; return r; };
    const int nbuck = (n_nodes + 255) >> 8;
    int*   rowp = (int*)(ws + alloc((size_t)(n_nodes + 1) * 4));
    float* inv  = (float*)(ws + alloc((size_t)n_nodes * 4));
    int*   ssrc = (int*)(ws + alloc((size_t)n_edges * 4));
    int*   bbase= (int*)(ws + alloc(MAXBUCK * 4));
    int*   bcur = (int*)(ws + alloc(MAXBUCK * 4));
    int*   tmpv = (int*)(ws + alloc((size_t)nbuck * BCAP * 4));
    const size_t pbytes = (size_t)n_nodes * PST * 2;  // one bf16 plane
    unsigned short* XAhi = (unsigned short*)(ws + alloc(pbytes));
    unsigned short* XAlo = (unsigned short*)(ws + alloc(pbytes));
    unsigned short* XBhi = (unsigned short*)(ws + alloc(pbytes));
    unsigned short* XBlo = (unsigned short*)(ws + alloc(pbytes));
    const size_t bfb = (size_t)PACKN * 8 * 2;
    unsigned short* B1h = (unsigned short*)(ws + alloc(bfb));
    unsigned short* B1l = (unsigned short*)(ws + alloc(bfb));
    unsigned short* B2h = (unsigned short*)(ws + alloc(bfb));
    unsigned short* B2l = (unsigned short*)(ws + alloc(bfb));
    unsigned short* B3h = (unsigned short*)(ws + alloc(bfb));
    unsigned short* B3l = (unsigned short*)(ws + alloc(bfb));

    hipMemsetAsync(bcur, 0, MAXBUCK * 4, stream);

    const int chunk = (n_edges + 255) / 256;

    // bucket CSR build: single edge pass (padded pre-sort) + tiny scan + build
    k_binscatter<<<256, 256, 0, stream>>>(src, dst, bcur, tmpv, n_edges, nbuck, chunk);
    k_binscan<<<1, 1024, 0, stream>>>(bcur, bbase, rowp, nbuck, n_nodes, n_edges);
    k_build<<<nbuck, 256, 0, stream>>>(tmpv, bbase, bcur, rowp, inv, ssrc,
                                       n_nodes, nbuck);

    k_pack3<<<(3 * PACKN + 255) / 256, 256, 0, stream>>>(
        W1l, W1r, W2l, W2r, W3l, W3r, B1h, B1l, B2h, B2l, B3h, B3l);

    const int nb16 = (n_nodes + 15) / 16;
    const int lgrid = (n_nodes + 31) / 32;

    k_cvt<<<nb16, 256, 0, stream>>>(x, XAhi, XAlo, n_nodes);

    // fused layers: wave-private pipelined aggr(LDS) + gemm (R15 structure)
    k_layer<<<lgrid, 128, 0, stream>>>(XAhi, XAlo, ssrc, rowp, inv, B1h, B1l, b1,
                                       XBhi, XBlo, 1, n_nodes);
    k_layer<<<lgrid, 128, 0, stream>>>(XBhi, XBlo, ssrc, rowp, inv, B2h, B2l, b2,
                                       XAhi, XAlo, 1, n_nodes);
    k_layer<<<lgrid, 128, 0, stream>>>(XAhi, XAlo, ssrc, rowp, inv, B3h, B3l, b3,
                                       XBhi, XBlo, 0, n_nodes);

    k_pool<<<n_graphs, 256, 0, stream>>>(XBhi, XBlo, batch, Wlin, blin, out, n_nodes);
}